// Round 2
// baseline (8229.304 us; speedup 1.0000x reference)
//
#include <hip/hip_runtime.h>
#include <cstdint>
#include <cstddef>

#define NEGV -1.0e9f

// ---------------------------------------------------------------------------
// K1: T = emb @ W + b   (f64 accumulate), T: [22][512]
// ---------------------------------------------------------------------------
__global__ void k_embed(const float* __restrict__ emb, const float* __restrict__ W,
                        const float* __restrict__ b, double* __restrict__ T) {
    int idx = blockIdx.x * blockDim.x + threadIdx.x;
    if (idx >= 22 * 512) return;
    int a = idx >> 9, d = idx & 511;
    double acc = (double)b[d];
    const float* er = emb + a * 512;
    for (int k = 0; k < 512; ++k) acc += (double)er[k] * (double)W[k * 512 + d];
    T[idx] = acc;
}

// ---------------------------------------------------------------------------
// K2: G = T @ T^T (22x22), u1/u2 = T @ Wg halves, A[b] via index sums
// ---------------------------------------------------------------------------
__global__ void k_gau(const double* __restrict__ T, const int* __restrict__ x,
                      const int* __restrict__ y, const float* __restrict__ Wg,
                      const float* __restrict__ bg,
                      double* __restrict__ G, double* __restrict__ Aout) {
    __shared__ double u1s[22], u2s[22];
    int t = threadIdx.x;
    if (t < 484) {
        int a = t / 22, c = t % 22;
        const double* ra = T + a * 512;
        const double* rc = T + c * 512;
        double acc = 0.0;
        for (int d = 0; d < 512; ++d) acc += ra[d] * rc[d];
        G[t] = acc;
    }
    if (t < 22) {
        double acc = 0.0;
        const double* ra = T + t * 512;
        for (int d = 0; d < 512; ++d) acc += ra[d] * (double)Wg[d];
        u1s[t] = acc;
    } else if (t >= 64 && t < 86) {
        int a = t - 64;
        double acc = 0.0;
        const double* ra = T + a * 512;
        for (int d = 0; d < 512; ++d) acc += ra[d] * (double)Wg[512 + d];
        u2s[a] = acc;
    }
    __syncthreads();
    int w = t >> 6, lane = t & 63;
    const int* xb = x + w * 1024;
    const int* yb = y + w * 1024;
    double s = 0.0;
    for (int i = lane; i < 1024; i += 64) s += u1s[xb[i]] + u2s[yb[i]];
    for (int off = 32; off > 0; off >>= 1) s += __shfl_down(s, off);
    if (lane == 0) Aout[w] = s * (1.0 / 1024.0) + (double)bg[0];
}

// ---------------------------------------------------------------------------
// K3: f32-faithful soft-NW forward (op-for-op replication of the reference's
//     float32 logaddexp chain + jax custom-JVP gradient weights, which are
//     UNNORMALIZED: each uses exp(x - stored_f32_lse)), then f32 backward.
//     FAITHFUL=true stores wd explicitly (3 floats/cell); fallback variant
//     (tiny ws) reconstructs wd = 1-wu-wl (less faithful).
// ---------------------------------------------------------------------------
template <bool FAITHFUL>
__global__ __launch_bounds__(1024) void k_dp(const int* __restrict__ x,
                                             const int* __restrict__ y,
                                             const double* __restrict__ G,
                                             const double* __restrict__ Aarr,
                                             float2* __restrict__ wbuf,
                                             float* __restrict__ wdbuf,
                                             float* __restrict__ out) {
    __shared__ float Gs[484];
    __shared__ int xs[1024], ys[1024];
    __shared__ float D[3][1025];   // f32 V on diagonals (ref is float32!)
    __shared__ float E[3][1026];   // grad diagonals

    const int b = blockIdx.x;
    const int t = threadIdx.x;
    const int i = t + 1;           // this thread owns row i (1..1024)

    if (t < 484) Gs[t] = (float)G[t];
    xs[t] = x[(b << 10) + t];
    ys[t] = y[(b << 10) + t];
    D[0][t + 1] = NEGV;
    D[1][t + 1] = NEGV;
    E[0][t] = 0.f; E[1][t] = 0.f; E[2][t] = 0.f;
    if (t == 0) {
        D[0][0] = 0.0f;            // V[0,0] = 0
        D[1][0] = NEGV;
        E[0][1024] = 0.f; E[0][1025] = 0.f;
        E[1][1024] = 0.f; E[1][1025] = 0.f;
        E[2][1024] = 0.f; E[2][1025] = 0.f;
    }
    __syncthreads();

    const float A = (float)Aarr[b];
    const float* Grow = Gs + xs[t] * 22;
    float2* wb = wbuf + ((size_t)b << 20);
    float*  wdb = wdbuf + ((size_t)b << 20);

    // ---- forward: diagonals k = i + j, all f32, op-faithful to reference ----
    for (int k = 2; k <= 2048; ++k) {
        const int cur = k % 3, p1 = (k + 2) % 3, p2 = (k + 1) % 3;
        const int j = k - i;
        if (j >= 1 && j <= 1024) {
            float vu  = D[p1][i - 1];      // V[i-1, j]
            float vdg = D[p2][i - 1];      // V[i-1, j-1]
            float vl  = D[p1][i];          // V[i,   j-1]
            float t1 = vu + A;             // f32 add, as reference
            float t2 = vl + A;
            // inner = logaddexp(t1, vdg)  (numpy/jax branch form)
            float di = t1 - vdg;
            float inner = (di > 0.f) ? (t1  + log1pf(expf(-di)))
                                     : (vdg + log1pf(expf(di)));
            // outer = logaddexp(inner, t2)
            float dw = inner - t2;
            float outer = (dw > 0.f) ? (inner + log1pf(expf(-dw)))
                                     : (t2    + log1pf(expf(dw)));
            D[cur][i] = Grow[ys[j - 1]] + outer;   // v = theta + outer (f32)
            // jax custom-JVP weights: exp(x - stored_out), chained, UNNORMALIZED
            float go1 = expf(inner - outer);
            float wlW = expf(t2 - outer);
            float wuW = go1 * expf(t1 - inner);
            size_t ci = ((size_t)t << 10) + (j - 1);
            wb[ci] = make_float2(wuW, wlW);
            if (FAITHFUL) wdb[ci] = go1 * expf(vdg - inner);
        }
        if (t == 0) D[cur][0] = NEGV;                 // V[0, k]
        if (i == k && k <= 1024) D[cur][k] = NEGV;    // V[k, 0]
        __syncthreads();
    }

    __syncthreads();

    float* ob = out + ((size_t)b << 20);

    // ---- backward: E[i,j] = Eu*wu(i+1,j) + Ed*wd(i+1,j+1) + El*wl(i,j+1) ----
    for (int k = 2048; k >= 2; --k) {
        const int cur = k % 3, n1 = (k + 1) % 3, n2 = (k + 2) % 3;
        const int j = k - i;
        if (j >= 1 && j <= 1024) {
            float e;
            if (k == 2048) {
                e = 1.0f;                  // E[N, M] = 1
            } else {
                float Eu = E[n1][i + 1];
                float Ed = E[n2][i + 1];
                float El = E[n1][i];
                int iw = (i < 1024) ? i : 1023;   // clamped; E factor is 0 there
                int jw = (j < 1024) ? j : 1023;
                float2 w_up = wb[((size_t)iw << 10) + (j - 1)];      // cell (i+1, j)
                float2 w_lf = wb[((size_t)(i - 1) << 10) + jw];      // cell (i,   j+1)
                float w_dd;
                if (FAITHFUL) {
                    w_dd = wdb[((size_t)iw << 10) + jw];             // cell (i+1, j+1)
                } else {
                    float2 w_dg = wb[((size_t)iw << 10) + jw];
                    w_dd = 1.0f - w_dg.x - w_dg.y;
                }
                e = Eu * w_up.x + Ed * w_dd + El * w_lf.y;
            }
            E[cur][i] = e;
            ob[((size_t)(j - 1) << 10) + (i - 1)] = e;   // out[b][j-1][i-1]
        } else {
            E[cur][i] = 0.f;
        }
        __syncthreads();
    }
}

// ---------------------------------------------------------------------------
extern "C" void kernel_launch(void* const* d_in, const int* in_sizes, int n_in,
                              void* d_out, int out_size, void* d_ws, size_t ws_size,
                              hipStream_t stream) {
    const int*   x   = (const int*)d_in[0];
    const int*   y   = (const int*)d_in[1];
    const float* emb = (const float*)d_in[2];
    const float* W   = (const float*)d_in[3];
    const float* b   = (const float*)d_in[4];
    const float* Wg  = (const float*)d_in[5];
    const float* bg  = (const float*)d_in[6];
    float* out = (float*)d_out;

    char* ws = (char*)d_ws;
    double* T    = (double*)(ws + 0);          // 90112 B
    double* G    = (double*)(ws + 90112);      // 3872 B
    double* Aarr = (double*)(ws + 94336);      // 64 B
    float2* wbuf = (float2*)(ws + 131072);     // 64 MiB: (wu, wl) per cell
    float* wdbuf = (float*)(ws + 131072 + ((size_t)64 << 20)); // 32 MiB: wd

    k_embed<<<44, 256, 0, stream>>>(emb, W, b, T);
    k_gau<<<1, 512, 0, stream>>>(T, x, y, Wg, bg, G, Aarr);

    const size_t need = 131072 + ((size_t)96 << 20);
    if (ws_size >= need) {
        k_dp<true><<<8, 1024, 0, stream>>>(x, y, G, Aarr, wbuf, wdbuf, out);
    } else {
        k_dp<false><<<8, 1024, 0, stream>>>(x, y, G, Aarr, wbuf, wdbuf, out);
    }
}

// Round 4
// 7231.061 us; speedup vs baseline: 1.1380x; 1.1380x over previous
//
#include <hip/hip_runtime.h>
#include <cstdint>
#include <cstddef>

#define NEGV -1.0e9f
#define TB 256
#define GT 4              // tiles per side (1024/TB)

// ---------------------------------------------------------------------------
// K1: T = emb @ W + b   (f64 accumulate), T: [22][512]
// ---------------------------------------------------------------------------
__global__ void k_embed(const float* __restrict__ emb, const float* __restrict__ W,
                        const float* __restrict__ b, double* __restrict__ T) {
    int idx = blockIdx.x * blockDim.x + threadIdx.x;
    if (idx >= 22 * 512) return;
    int a = idx >> 9, d = idx & 511;
    double acc = (double)b[d];
    const float* er = emb + a * 512;
    for (int k = 0; k < 512; ++k) acc += (double)er[k] * (double)W[k * 512 + d];
    T[idx] = acc;
}

// ---------------------------------------------------------------------------
// K2: G = T @ T^T (22x22), u1/u2 = T @ Wg halves, A[b] via index sums
// ---------------------------------------------------------------------------
__global__ void k_gau(const double* __restrict__ T, const int* __restrict__ x,
                      const int* __restrict__ y, const float* __restrict__ Wg,
                      const float* __restrict__ bg,
                      double* __restrict__ G, double* __restrict__ Aout) {
    __shared__ double u1s[22], u2s[22];
    int t = threadIdx.x;
    if (t < 484) {
        int a = t / 22, c = t % 22;
        const double* ra = T + a * 512;
        const double* rc = T + c * 512;
        double acc = 0.0;
        for (int d = 0; d < 512; ++d) acc += ra[d] * rc[d];
        G[t] = acc;
    }
    if (t < 22) {
        double acc = 0.0;
        const double* ra = T + t * 512;
        for (int d = 0; d < 512; ++d) acc += ra[d] * (double)Wg[d];
        u1s[t] = acc;
    } else if (t >= 64 && t < 86) {
        int a = t - 64;
        double acc = 0.0;
        const double* ra = T + a * 512;
        for (int d = 0; d < 512; ++d) acc += ra[d] * (double)Wg[512 + d];
        u2s[a] = acc;
    }
    __syncthreads();
    int w = t >> 6, lane = t & 63;
    const int* xb = x + w * 1024;
    const int* yb = y + w * 1024;
    double s = 0.0;
    for (int i = lane; i < 1024; i += 64) s += u1s[xb[i]] + u2s[yb[i]];
    for (int off = 32; off > 0; off >>= 1) s += __shfl_down(s, off);
    if (lane == 0) Aout[w] = s * (1.0 / 1024.0) + (double)bg[0];
}

// ---------------------------------------------------------------------------
// K3a: init V boundary (row 0 / col 0). Vbuf[b][i][j], stride 1025.
// ---------------------------------------------------------------------------
__global__ void k_vinit(float* __restrict__ Vbuf) {
    int b = blockIdx.x, t = threadIdx.x;
    float* Vb = Vbuf + (size_t)b * (1025 * 1025);
    Vb[t] = (t == 0) ? 0.0f : NEGV;                 // V[0][t]
    if (t == 0) Vb[1024] = NEGV;                    // V[0][1024]
    Vb[(size_t)(t + 1) * 1025] = NEGV;              // V[t+1][0]
}

// ---------------------------------------------------------------------------
// K3b: tiled forward wavefront. One block per (batch, tile) on tile-diagonal
//      d = r + c. Stores V (f32) only; per-cell ops bit-identical to the
//      verified monolithic kernel (same expf/log1pf sequence, same inputs).
// ---------------------------------------------------------------------------
__global__ __launch_bounds__(256) void k_fwd(const int* __restrict__ x,
                                             const int* __restrict__ y,
                                             const double* __restrict__ G,
                                             const double* __restrict__ Aarr,
                                             float* __restrict__ Vbuf,
                                             int d, int cnt, int rlo) {
    __shared__ float Gs[484];
    __shared__ float topv[TB + 1], leftv[TB + 1];
    __shared__ float D[3][TB];
    __shared__ int ys_t[TB];

    const int t = threadIdx.x;
    const int b = blockIdx.x / cnt;
    const int r = rlo + (blockIdx.x % cnt);
    const int c = d - r;
    float* Vb = Vbuf + (size_t)b * (1025 * 1025);

    for (int q = t; q < 484; q += TB) Gs[q] = (float)G[q];   // FIX: strided load
    ys_t[t] = y[(b << 10) + c * TB + t];
    const int xs = x[(b << 10) + r * TB + t];

    topv[t]  = Vb[(size_t)(TB * r) * 1025 + TB * c + t];
    leftv[t] = Vb[(size_t)(TB * r + t) * 1025 + TB * c];
    if (t == 0) {
        topv[TB]  = Vb[(size_t)(TB * r) * 1025 + TB * c + TB];
        leftv[TB] = Vb[(size_t)(TB * r + TB) * 1025 + TB * c];
    }
    __syncthreads();

    const float A = (float)Aarr[b];
    const float* Grow = Gs + xs * 22;
    const int li = t;

    for (int s = 0; s < 2 * TB - 1; ++s) {
        const int cur = s % 3, p1 = (s + 2) % 3, p2 = (s + 1) % 3;
        const int lj = s - li;
        if (lj >= 0 && lj < TB) {
            float vu  = (li > 0) ? D[p1][li - 1] : topv[lj + 1];
            float vdg = (li > 0) ? ((lj > 0) ? D[p2][li - 1] : leftv[li]) : topv[lj];
            float vl  = (lj > 0) ? D[p1][li] : leftv[li + 1];
            float t1 = vu + A;
            float t2 = vl + A;
            float di = t1 - vdg;
            float inner = (di > 0.f) ? (t1  + log1pf(expf(-di)))
                                     : (vdg + log1pf(expf(di)));
            float dw = inner - t2;
            float outer = (dw > 0.f) ? (inner + log1pf(expf(-dw)))
                                     : (t2    + log1pf(expf(dw)));
            float v = Grow[ys_t[lj]] + outer;
            D[cur][li] = v;
            Vb[(size_t)(TB * r + 1 + li) * 1025 + (TB * c + 1 + lj)] = v;
        }
        __syncthreads();
    }
}

// ---------------------------------------------------------------------------
// K4: flat weight kernel — recompute each cell's softmax weights from stored
//     V neighbors (bit-identical inputs -> bit-identical weights), write the
//     same wbuf/wdbuf layout the backward expects.
// ---------------------------------------------------------------------------
__global__ __launch_bounds__(256) void k_weights(const double* __restrict__ Aarr,
                                                 const float* __restrict__ Vbuf,
                                                 float2* __restrict__ wbuf,
                                                 float* __restrict__ wdbuf) {
    int idx = blockIdx.x * 256 + threadIdx.x;
    int b = idx >> 20;
    int cell = idx & 1048575;
    int i = (cell >> 10) + 1;        // 1..1024
    int j = (cell & 1023) + 1;       // 1..1024
    const float* Vb = Vbuf + (size_t)b * (1025 * 1025);
    float vu  = Vb[(size_t)(i - 1) * 1025 + j];
    float vdg = Vb[(size_t)(i - 1) * 1025 + (j - 1)];
    float vl  = Vb[(size_t)i * 1025 + (j - 1)];
    float A = (float)Aarr[b];
    float t1 = vu + A;
    float t2 = vl + A;
    float di = t1 - vdg;
    float inner = (di > 0.f) ? (t1  + log1pf(expf(-di)))
                             : (vdg + log1pf(expf(di)));
    float dw = inner - t2;
    float outer = (dw > 0.f) ? (inner + log1pf(expf(-dw)))
                             : (t2    + log1pf(expf(dw)));
    float go1 = expf(inner - outer);
    float wlW = expf(t2 - outer);
    float wuW = go1 * expf(t1 - inner);
    size_t ci = ((size_t)b << 20) + ((size_t)(i - 1) << 10) + (j - 1);
    wbuf[ci] = make_float2(wuW, wlW);
    wdbuf[ci] = go1 * expf(vdg - inner);
}

// ---------------------------------------------------------------------------
// K5: tiled backward wavefront (reverse tile-diagonals). E-halos read from
//     `out` (written by earlier launches); 0 beyond boundary; seed at
//     (1024,1024). Per-cell math verbatim from the verified monolithic bwd.
// ---------------------------------------------------------------------------
__global__ __launch_bounds__(256) void k_bwdt(const float2* __restrict__ wbuf,
                                              const float* __restrict__ wdbuf,
                                              float* __restrict__ out,
                                              int d, int cnt, int rlo) {
    __shared__ float D[3][TB];
    __shared__ float botE[TB + 1];
    __shared__ float rightE[TB];

    const int t = threadIdx.x;
    const int b = blockIdx.x / cnt;
    const int r = rlo + (blockIdx.x % cnt);
    const int c = d - r;
    const float2* wb  = wbuf + ((size_t)b << 20);
    const float*  wdb = wdbuf + ((size_t)b << 20);
    float* ob = out + ((size_t)b << 20);

    const int gi = TB * r + TB + 1;   // bottom halo row (global i)
    const int gj = TB * c + TB + 1;   // right halo col (global j)
    botE[t]   = (gi <= 1024) ? ob[((size_t)(TB * c + t) << 10) + (gi - 1)] : 0.f;
    rightE[t] = (gj <= 1024) ? ob[((size_t)(gj - 1) << 10) + (TB * r + t)] : 0.f;
    if (t == 0)
        botE[TB] = (gi <= 1024 && gj <= 1024)
                 ? ob[((size_t)(gj - 1) << 10) + (gi - 1)] : 0.f;
    __syncthreads();

    const int li = t;
    const int i = TB * r + 1 + li;

    for (int s = 2 * TB - 2; s >= 0; --s) {
        const int cur = s % 3, n1 = (s + 1) % 3, n2 = (s + 2) % 3;
        const int lj = s - li;
        if (lj >= 0 && lj < TB) {
            const int j = TB * c + 1 + lj;
            float e;
            if (i == 1024 && j == 1024) {
                e = 1.0f;                               // E[N, M] = 1
            } else {
                float Eu = (li < TB - 1) ? D[n1][li + 1] : botE[lj];
                float Ed = (li < TB - 1) ? ((lj < TB - 1) ? D[n2][li + 1]
                                                          : rightE[li + 1])
                                         : botE[lj + 1];
                float El = (lj < TB - 1) ? D[n1][li] : rightE[li];
                int iw = (i < 1024) ? i : 1023;
                int jw = (j < 1024) ? j : 1023;
                float2 w_up = wb[((size_t)iw << 10) + (j - 1)];
                float2 w_lf = wb[((size_t)(i - 1) << 10) + jw];
                float  w_dd = wdb[((size_t)iw << 10) + jw];
                e = Eu * w_up.x + Ed * w_dd + El * w_lf.y;
            }
            D[cur][li] = e;
            ob[((size_t)(j - 1) << 10) + (i - 1)] = e;   // out[b][j-1][i-1]
        }
        __syncthreads();
    }
}

// ---------------------------------------------------------------------------
// Fallback: round-2 monolithic forward+backward (used only if ws too small).
// ---------------------------------------------------------------------------
template <bool FAITHFUL>
__global__ __launch_bounds__(1024) void k_dp(const int* __restrict__ x,
                                             const int* __restrict__ y,
                                             const double* __restrict__ G,
                                             const double* __restrict__ Aarr,
                                             float2* __restrict__ wbuf,
                                             float* __restrict__ wdbuf,
                                             float* __restrict__ out) {
    __shared__ float Gs[484];
    __shared__ int xs[1024], ys[1024];
    __shared__ float D[3][1025];
    __shared__ float E[3][1026];

    const int b = blockIdx.x;
    const int t = threadIdx.x;
    const int i = t + 1;

    if (t < 484) Gs[t] = (float)G[t];
    xs[t] = x[(b << 10) + t];
    ys[t] = y[(b << 10) + t];
    D[0][t + 1] = NEGV;
    D[1][t + 1] = NEGV;
    E[0][t] = 0.f; E[1][t] = 0.f; E[2][t] = 0.f;
    if (t == 0) {
        D[0][0] = 0.0f;
        D[1][0] = NEGV;
        E[0][1024] = 0.f; E[0][1025] = 0.f;
        E[1][1024] = 0.f; E[1][1025] = 0.f;
        E[2][1024] = 0.f; E[2][1025] = 0.f;
    }
    __syncthreads();

    const float A = (float)Aarr[b];
    const float* Grow = Gs + xs[t] * 22;
    float2* wb = wbuf + ((size_t)b << 20);
    float*  wdb = wdbuf + ((size_t)b << 20);

    for (int k = 2; k <= 2048; ++k) {
        const int cur = k % 3, p1 = (k + 2) % 3, p2 = (k + 1) % 3;
        const int j = k - i;
        if (j >= 1 && j <= 1024) {
            float vu  = D[p1][i - 1];
            float vdg = D[p2][i - 1];
            float vl  = D[p1][i];
            float t1 = vu + A;
            float t2 = vl + A;
            float di = t1 - vdg;
            float inner = (di > 0.f) ? (t1  + log1pf(expf(-di)))
                                     : (vdg + log1pf(expf(di)));
            float dw = inner - t2;
            float outer = (dw > 0.f) ? (inner + log1pf(expf(-dw)))
                                     : (t2    + log1pf(expf(dw)));
            D[cur][i] = Grow[ys[j - 1]] + outer;
            float go1 = expf(inner - outer);
            float wlW = expf(t2 - outer);
            float wuW = go1 * expf(t1 - inner);
            size_t ci = ((size_t)t << 10) + (j - 1);
            wb[ci] = make_float2(wuW, wlW);
            if (FAITHFUL) wdb[ci] = go1 * expf(vdg - inner);
        }
        if (t == 0) D[cur][0] = NEGV;
        if (i == k && k <= 1024) D[cur][k] = NEGV;
        __syncthreads();
    }

    __syncthreads();

    float* ob = out + ((size_t)b << 20);

    for (int k = 2048; k >= 2; --k) {
        const int cur = k % 3, n1 = (k + 1) % 3, n2 = (k + 2) % 3;
        const int j = k - i;
        if (j >= 1 && j <= 1024) {
            float e;
            if (k == 2048) {
                e = 1.0f;
            } else {
                float Eu = E[n1][i + 1];
                float Ed = E[n2][i + 1];
                float El = E[n1][i];
                int iw = (i < 1024) ? i : 1023;
                int jw = (j < 1024) ? j : 1023;
                float2 w_up = wb[((size_t)iw << 10) + (j - 1)];
                float2 w_lf = wb[((size_t)(i - 1) << 10) + jw];
                float w_dd;
                if (FAITHFUL) {
                    w_dd = wdb[((size_t)iw << 10) + jw];
                } else {
                    float2 w_dg = wb[((size_t)iw << 10) + jw];
                    w_dd = 1.0f - w_dg.x - w_dg.y;
                }
                e = Eu * w_up.x + Ed * w_dd + El * w_lf.y;
            }
            E[cur][i] = e;
            ob[((size_t)(j - 1) << 10) + (i - 1)] = e;
        } else {
            E[cur][i] = 0.f;
        }
        __syncthreads();
    }
}

// ---------------------------------------------------------------------------
extern "C" void kernel_launch(void* const* d_in, const int* in_sizes, int n_in,
                              void* d_out, int out_size, void* d_ws, size_t ws_size,
                              hipStream_t stream) {
    const int*   x   = (const int*)d_in[0];
    const int*   y   = (const int*)d_in[1];
    const float* emb = (const float*)d_in[2];
    const float* W   = (const float*)d_in[3];
    const float* b   = (const float*)d_in[4];
    const float* Wg  = (const float*)d_in[5];
    const float* bg  = (const float*)d_in[6];
    float* out = (float*)d_out;

    char* ws = (char*)d_ws;
    double* T    = (double*)(ws + 0);                       // 90112 B
    double* G    = (double*)(ws + 90112);                   // 3872 B
    double* Aarr = (double*)(ws + 94336);                   // 64 B
    float2* wbuf = (float2*)(ws + 131072);                  // 64 MiB
    float* wdbuf = (float*)(ws + 131072 + ((size_t)64 << 20));   // 32 MiB
    float* Vbuf  = (float*)(ws + 131072 + ((size_t)96 << 20));   // 33.6 MB

    k_embed<<<44, 256, 0, stream>>>(emb, W, b, T);
    k_gau<<<1, 512, 0, stream>>>(T, x, y, Wg, bg, G, Aarr);

    const size_t need_old = 131072 + ((size_t)96 << 20);
    const size_t need_new = need_old + (size_t)8 * 1025 * 1025 * 4;

    if (ws_size >= need_new) {
        k_vinit<<<8, 1024, 0, stream>>>(Vbuf);
        for (int d = 0; d < 2 * GT - 1; ++d) {
            int rlo = (d - (GT - 1) > 0) ? d - (GT - 1) : 0;
            int rhi = (d < GT - 1) ? d : GT - 1;
            int cnt = rhi - rlo + 1;
            k_fwd<<<cnt * 8, TB, 0, stream>>>(x, y, G, Aarr, Vbuf, d, cnt, rlo);
        }
        k_weights<<<8 * 1024 * 1024 / 256, 256, 0, stream>>>(Aarr, Vbuf, wbuf, wdbuf);
        for (int d = 2 * GT - 2; d >= 0; --d) {
            int rlo = (d - (GT - 1) > 0) ? d - (GT - 1) : 0;
            int rhi = (d < GT - 1) ? d : GT - 1;
            int cnt = rhi - rlo + 1;
            k_bwdt<<<cnt * 8, TB, 0, stream>>>(wbuf, wdbuf, out, d, cnt, rlo);
        }
    } else if (ws_size >= need_old) {
        k_dp<true><<<8, 1024, 0, stream>>>(x, y, G, Aarr, wbuf, wdbuf, out);
    } else {
        k_dp<false><<<8, 1024, 0, stream>>>(x, y, G, Aarr, wbuf, wdbuf, out);
    }
}

// Round 5
// 7161.743 us; speedup vs baseline: 1.1491x; 1.0097x over previous
//
#include <hip/hip_runtime.h>
#include <cstdint>
#include <cstddef>

#define NEGV -1.0e9f
#define TB 256
#define GT 4              // tiles per side (1024/TB)

// lgkm-only barrier: LDS-producer/consumer sync WITHOUT draining the
// global-store queue (avoids the s_waitcnt vmcnt(0) the compiler emits
// before s_barrier for __syncthreads).
__device__ __forceinline__ void lgkm_barrier() {
    asm volatile("s_waitcnt lgkmcnt(0)" ::: "memory");
    __builtin_amdgcn_s_barrier();
}

// ---------------------------------------------------------------------------
// K1: T = emb @ W + b   (f64 accumulate), T: [22][512]
// ---------------------------------------------------------------------------
__global__ void k_embed(const float* __restrict__ emb, const float* __restrict__ W,
                        const float* __restrict__ b, double* __restrict__ T) {
    int idx = blockIdx.x * blockDim.x + threadIdx.x;
    if (idx >= 22 * 512) return;
    int a = idx >> 9, d = idx & 511;
    double acc = (double)b[d];
    const float* er = emb + a * 512;
    for (int k = 0; k < 512; ++k) acc += (double)er[k] * (double)W[k * 512 + d];
    T[idx] = acc;
}

// ---------------------------------------------------------------------------
// K2: G = T @ T^T (22x22), u1/u2 = T @ Wg halves, A[b] via index sums
// ---------------------------------------------------------------------------
__global__ void k_gau(const double* __restrict__ T, const int* __restrict__ x,
                      const int* __restrict__ y, const float* __restrict__ Wg,
                      const float* __restrict__ bg,
                      double* __restrict__ G, double* __restrict__ Aout) {
    __shared__ double u1s[22], u2s[22];
    int t = threadIdx.x;
    if (t < 484) {
        int a = t / 22, c = t % 22;
        const double* ra = T + a * 512;
        const double* rc = T + c * 512;
        double acc = 0.0;
        for (int d = 0; d < 512; ++d) acc += ra[d] * rc[d];
        G[t] = acc;
    }
    if (t < 22) {
        double acc = 0.0;
        const double* ra = T + t * 512;
        for (int d = 0; d < 512; ++d) acc += ra[d] * (double)Wg[d];
        u1s[t] = acc;
    } else if (t >= 64 && t < 86) {
        int a = t - 64;
        double acc = 0.0;
        const double* ra = T + a * 512;
        for (int d = 0; d < 512; ++d) acc += ra[d] * (double)Wg[512 + d];
        u2s[a] = acc;
    }
    __syncthreads();
    int w = t >> 6, lane = t & 63;
    const int* xb = x + w * 1024;
    const int* yb = y + w * 1024;
    double s = 0.0;
    for (int i = lane; i < 1024; i += 64) s += u1s[xb[i]] + u2s[yb[i]];
    for (int off = 32; off > 0; off >>= 1) s += __shfl_down(s, off);
    if (lane == 0) Aout[w] = s * (1.0 / 1024.0) + (double)bg[0];
}

// ---------------------------------------------------------------------------
// K3a: init V boundary (row 0 / col 0). Vbuf[b][i][j], stride 1025.
// ---------------------------------------------------------------------------
__global__ void k_vinit(float* __restrict__ Vbuf) {
    int b = blockIdx.x, t = threadIdx.x;
    float* Vb = Vbuf + (size_t)b * (1025 * 1025);
    Vb[t] = (t == 0) ? 0.0f : NEGV;                 // V[0][t]
    if (t == 0) Vb[1024] = NEGV;                    // V[0][1024]
    Vb[(size_t)(t + 1) * 1025] = NEGV;              // V[t+1][0]
}

// ---------------------------------------------------------------------------
// K3b: tiled forward wavefront. Register-carried vdg/vl (bit-identical to the
//      LDS round-trip), one ds_read (vu) per step, theta LDS-prefetched,
//      lgkm-only barrier so V global stores stay in flight.
// ---------------------------------------------------------------------------
__global__ __launch_bounds__(256) void k_fwd(const int* __restrict__ x,
                                             const int* __restrict__ y,
                                             const double* __restrict__ G,
                                             const double* __restrict__ Aarr,
                                             float* __restrict__ Vbuf,
                                             int d, int cnt, int rlo) {
    __shared__ float Gs[484];
    __shared__ float topv[TB + 1], leftv[TB + 1];
    __shared__ float Dp[2][TB];
    __shared__ int ys_t[TB];

    const int t = threadIdx.x;
    const int b = blockIdx.x / cnt;
    const int r = rlo + (blockIdx.x % cnt);
    const int c = d - r;
    float* Vb = Vbuf + (size_t)b * (1025 * 1025);

    for (int q = t; q < 484; q += TB) Gs[q] = (float)G[q];
    ys_t[t] = y[(b << 10) + c * TB + t];
    const int xs = x[(b << 10) + r * TB + t];

    topv[t]  = Vb[(size_t)(TB * r) * 1025 + TB * c + t];
    leftv[t] = Vb[(size_t)(TB * r + t) * 1025 + TB * c];
    if (t == 0) {
        topv[TB]  = Vb[(size_t)(TB * r) * 1025 + TB * c + TB];
        leftv[TB] = Vb[(size_t)(TB * r + TB) * 1025 + TB * c];
    }
    __syncthreads();

    const float A = (float)Aarr[b];
    const float* Grow = Gs + xs * 22;
    const int li = t;
    float* vout = Vb + (size_t)(TB * r + 1 + li) * 1025 + (TB * c + 1);

    float vdg_r = 0.f, vl_r = 0.f, th_c = 0.f, th_n = 0.f;

    for (int s = 0; s < 2 * TB - 1; ++s) {
        const int lj = s - li;
        if (lj >= 0 && lj < TB) {
            if (lj == 0) {                         // first active step: seed carries
                vdg_r = (li > 0) ? leftv[li] : topv[0];
                vl_r  = leftv[li + 1];
                th_c  = Grow[ys_t[0]];
            }
            float vu = (li > 0) ? Dp[(s + 1) & 1][li - 1] : topv[lj + 1];
            if (lj + 1 < TB) th_n = Grow[ys_t[lj + 1]];   // theta prefetch
            float t1 = vu + A;
            float t2 = vl_r + A;
            float di = t1 - vdg_r;
            float inner = (di > 0.f) ? (t1    + log1pf(expf(-di)))
                                     : (vdg_r + log1pf(expf(di)));
            float dw = inner - t2;
            float outer = (dw > 0.f) ? (inner + log1pf(expf(-dw)))
                                     : (t2    + log1pf(expf(dw)));
            float v = th_c + outer;
            Dp[s & 1][li] = v;
            vout[lj] = v;                          // store stays in flight
            vdg_r = vu; vl_r = v; th_c = th_n;
        }
        lgkm_barrier();
    }
}

// ---------------------------------------------------------------------------
// K4: flat weight kernel — recompute each cell's softmax weights from stored
//     V neighbors (bit-identical inputs -> bit-identical weights).
// ---------------------------------------------------------------------------
__global__ __launch_bounds__(256) void k_weights(const double* __restrict__ Aarr,
                                                 const float* __restrict__ Vbuf,
                                                 float2* __restrict__ wbuf,
                                                 float* __restrict__ wdbuf) {
    int idx = blockIdx.x * 256 + threadIdx.x;
    int b = idx >> 20;
    int cell = idx & 1048575;
    int i = (cell >> 10) + 1;        // 1..1024
    int j = (cell & 1023) + 1;       // 1..1024
    const float* Vb = Vbuf + (size_t)b * (1025 * 1025);
    float vu  = Vb[(size_t)(i - 1) * 1025 + j];
    float vdg = Vb[(size_t)(i - 1) * 1025 + (j - 1)];
    float vl  = Vb[(size_t)i * 1025 + (j - 1)];
    float A = (float)Aarr[b];
    float t1 = vu + A;
    float t2 = vl + A;
    float di = t1 - vdg;
    float inner = (di > 0.f) ? (t1  + log1pf(expf(-di)))
                             : (vdg + log1pf(expf(di)));
    float dw = inner - t2;
    float outer = (dw > 0.f) ? (inner + log1pf(expf(-dw)))
                             : (t2    + log1pf(expf(dw)));
    float go1 = expf(inner - outer);
    float wlW = expf(t2 - outer);
    float wuW = go1 * expf(t1 - inner);
    size_t ci = ((size_t)b << 20) + ((size_t)(i - 1) << 10) + (j - 1);
    wbuf[ci] = make_float2(wuW, wlW);
    wdbuf[ci] = go1 * expf(vdg - inner);
}

// ---------------------------------------------------------------------------
// K5: tiled backward wavefront. Register-carried Ed/El, weight loads
//     prefetched one step ahead, lgkm-only barrier (E stores in flight).
// ---------------------------------------------------------------------------
__global__ __launch_bounds__(256) void k_bwdt(const float2* __restrict__ wbuf,
                                              const float* __restrict__ wdbuf,
                                              float* __restrict__ out,
                                              int d, int cnt, int rlo) {
    __shared__ float EP[2][TB];
    __shared__ float botE[TB + 1];
    __shared__ float rightE[TB + 1];

    const int t = threadIdx.x;
    const int b = blockIdx.x / cnt;
    const int r = rlo + (blockIdx.x % cnt);
    const int c = d - r;
    const float2* wb  = wbuf + ((size_t)b << 20);
    const float*  wdb = wdbuf + ((size_t)b << 20);
    float* ob = out + ((size_t)b << 20);

    const int gi = TB * r + TB + 1;   // bottom halo row (global i)
    const int gj = TB * c + TB + 1;   // right halo col (global j)
    botE[t]   = (gi <= 1024) ? ob[((size_t)(TB * c + t) << 10) + (gi - 1)] : 0.f;
    rightE[t] = (gj <= 1024) ? ob[((size_t)(gj - 1) << 10) + (TB * r + t)] : 0.f;
    if (t == 0) {
        float corner = (gi <= 1024 && gj <= 1024)
                     ? ob[((size_t)(gj - 1) << 10) + (gi - 1)] : 0.f;
        botE[TB]   = corner;
        rightE[TB] = corner;
    }
    __syncthreads();

    const int li = t;
    const int i = TB * r + 1 + li;
    const int iw = (i < 1024) ? i : 1023;

    float ed_r = 0.f, el_r = 0.f;
    float puw = 0.f, plw = 0.f, pdw = 0.f;    // this step's weights

    for (int s = 2 * TB - 2; s >= 0; --s) {
        const int lj = s - li;
        if (lj >= 0 && lj < TB) {
            const int j = TB * c + 1 + lj;
            if (lj == TB - 1) {                  // first active step: seed
                ed_r = rightE[li + 1];
                el_r = rightE[li];
                int jw = (j < 1024) ? j : 1023;
                float2 a1 = wb[((size_t)iw << 10) + (j - 1)];
                float2 a2 = wb[((size_t)(i - 1) << 10) + jw];
                float  a3 = wdb[((size_t)iw << 10) + jw];
                puw = a1.x; plw = a2.y; pdw = a3;
            }
            // prefetch next step's weights (cell (i, j-1)); jn<=1023 so jw=jn
            float npu = 0.f, npl = 0.f, npd = 0.f;
            if (lj > 0) {
                const int jn = j - 1;
                float2 a1 = wb[((size_t)iw << 10) + (jn - 1)];
                float2 a2 = wb[((size_t)(i - 1) << 10) + jn];
                float  a3 = wdb[((size_t)iw << 10) + jn];
                npu = a1.x; npl = a2.y; npd = a3;
            }
            float eu = (li < TB - 1) ? EP[(s + 1) & 1][li + 1] : botE[lj];
            float e;
            if (i == 1024 && j == 1024) e = 1.0f;   // seed E[N,M]=1
            else e = eu * puw + ed_r * pdw + el_r * plw;
            EP[s & 1][li] = e;
            ob[((size_t)(j - 1) << 10) + (i - 1)] = e;   // in-flight store
            ed_r = eu; el_r = e;
            puw = npu; plw = npl; pdw = npd;
        }
        lgkm_barrier();
    }
}

// ---------------------------------------------------------------------------
// Fallback: round-2 monolithic forward+backward (used only if ws too small).
// ---------------------------------------------------------------------------
template <bool FAITHFUL>
__global__ __launch_bounds__(1024) void k_dp(const int* __restrict__ x,
                                             const int* __restrict__ y,
                                             const double* __restrict__ G,
                                             const double* __restrict__ Aarr,
                                             float2* __restrict__ wbuf,
                                             float* __restrict__ wdbuf,
                                             float* __restrict__ out) {
    __shared__ float Gs[484];
    __shared__ int xs[1024], ys[1024];
    __shared__ float D[3][1025];
    __shared__ float E[3][1026];

    const int b = blockIdx.x;
    const int t = threadIdx.x;
    const int i = t + 1;

    if (t < 484) Gs[t] = (float)G[t];
    xs[t] = x[(b << 10) + t];
    ys[t] = y[(b << 10) + t];
    D[0][t + 1] = NEGV;
    D[1][t + 1] = NEGV;
    E[0][t] = 0.f; E[1][t] = 0.f; E[2][t] = 0.f;
    if (t == 0) {
        D[0][0] = 0.0f;
        D[1][0] = NEGV;
        E[0][1024] = 0.f; E[0][1025] = 0.f;
        E[1][1024] = 0.f; E[1][1025] = 0.f;
        E[2][1024] = 0.f; E[2][1025] = 0.f;
    }
    __syncthreads();

    const float A = (float)Aarr[b];
    const float* Grow = Gs + xs[t] * 22;
    float2* wb = wbuf + ((size_t)b << 20);
    float*  wdb = wdbuf + ((size_t)b << 20);

    for (int k = 2; k <= 2048; ++k) {
        const int cur = k % 3, p1 = (k + 2) % 3, p2 = (k + 1) % 3;
        const int j = k - i;
        if (j >= 1 && j <= 1024) {
            float vu  = D[p1][i - 1];
            float vdg = D[p2][i - 1];
            float vl  = D[p1][i];
            float t1 = vu + A;
            float t2 = vl + A;
            float di = t1 - vdg;
            float inner = (di > 0.f) ? (t1  + log1pf(expf(-di)))
                                     : (vdg + log1pf(expf(di)));
            float dw = inner - t2;
            float outer = (dw > 0.f) ? (inner + log1pf(expf(-dw)))
                                     : (t2    + log1pf(expf(dw)));
            D[cur][i] = Grow[ys[j - 1]] + outer;
            float go1 = expf(inner - outer);
            float wlW = expf(t2 - outer);
            float wuW = go1 * expf(t1 - inner);
            size_t ci = ((size_t)t << 10) + (j - 1);
            wb[ci] = make_float2(wuW, wlW);
            if (FAITHFUL) wdb[ci] = go1 * expf(vdg - inner);
        }
        if (t == 0) D[cur][0] = NEGV;
        if (i == k && k <= 1024) D[cur][k] = NEGV;
        __syncthreads();
    }

    __syncthreads();

    float* ob = out + ((size_t)b << 20);

    for (int k = 2048; k >= 2; --k) {
        const int cur = k % 3, n1 = (k + 1) % 3, n2 = (k + 2) % 3;
        const int j = k - i;
        if (j >= 1 && j <= 1024) {
            float e;
            if (k == 2048) {
                e = 1.0f;
            } else {
                float Eu = E[n1][i + 1];
                float Ed = E[n2][i + 1];
                float El = E[n1][i];
                int iw = (i < 1024) ? i : 1023;
                int jw = (j < 1024) ? j : 1023;
                float2 w_up = wb[((size_t)iw << 10) + (j - 1)];
                float2 w_lf = wb[((size_t)(i - 1) << 10) + jw];
                float w_dd;
                if (FAITHFUL) {
                    w_dd = wdb[((size_t)iw << 10) + jw];
                } else {
                    float2 w_dg = wb[((size_t)iw << 10) + jw];
                    w_dd = 1.0f - w_dg.x - w_dg.y;
                }
                e = Eu * w_up.x + Ed * w_dd + El * w_lf.y;
            }
            E[cur][i] = e;
            ob[((size_t)(j - 1) << 10) + (i - 1)] = e;
        } else {
            E[cur][i] = 0.f;
        }
        __syncthreads();
    }
}

// ---------------------------------------------------------------------------
extern "C" void kernel_launch(void* const* d_in, const int* in_sizes, int n_in,
                              void* d_out, int out_size, void* d_ws, size_t ws_size,
                              hipStream_t stream) {
    const int*   x   = (const int*)d_in[0];
    const int*   y   = (const int*)d_in[1];
    const float* emb = (const float*)d_in[2];
    const float* W   = (const float*)d_in[3];
    const float* b   = (const float*)d_in[4];
    const float* Wg  = (const float*)d_in[5];
    const float* bg  = (const float*)d_in[6];
    float* out = (float*)d_out;

    char* ws = (char*)d_ws;
    double* T    = (double*)(ws + 0);                       // 90112 B
    double* G    = (double*)(ws + 90112);                   // 3872 B
    double* Aarr = (double*)(ws + 94336);                   // 64 B
    float2* wbuf = (float2*)(ws + 131072);                  // 64 MiB
    float* wdbuf = (float*)(ws + 131072 + ((size_t)64 << 20));   // 32 MiB
    float* Vbuf  = (float*)(ws + 131072 + ((size_t)96 << 20));   // 33.6 MB

    k_embed<<<44, 256, 0, stream>>>(emb, W, b, T);
    k_gau<<<1, 512, 0, stream>>>(T, x, y, Wg, bg, G, Aarr);

    const size_t need_old = 131072 + ((size_t)96 << 20);
    const size_t need_new = need_old + (size_t)8 * 1025 * 1025 * 4;

    if (ws_size >= need_new) {
        k_vinit<<<8, 1024, 0, stream>>>(Vbuf);
        for (int d = 0; d < 2 * GT - 1; ++d) {
            int rlo = (d - (GT - 1) > 0) ? d - (GT - 1) : 0;
            int rhi = (d < GT - 1) ? d : GT - 1;
            int cnt = rhi - rlo + 1;
            k_fwd<<<cnt * 8, TB, 0, stream>>>(x, y, G, Aarr, Vbuf, d, cnt, rlo);
        }
        k_weights<<<8 * 1024 * 1024 / 256, 256, 0, stream>>>(Aarr, Vbuf, wbuf, wdbuf);
        for (int d = 2 * GT - 2; d >= 0; --d) {
            int rlo = (d - (GT - 1) > 0) ? d - (GT - 1) : 0;
            int rhi = (d < GT - 1) ? d : GT - 1;
            int cnt = rhi - rlo + 1;
            k_bwdt<<<cnt * 8, TB, 0, stream>>>(wbuf, wdbuf, out, d, cnt, rlo);
        }
    } else if (ws_size >= need_old) {
        k_dp<true><<<8, 1024, 0, stream>>>(x, y, G, Aarr, wbuf, wdbuf, out);
    } else {
        k_dp<false><<<8, 1024, 0, stream>>>(x, y, G, Aarr, wbuf, wdbuf, out);
    }
}

// Round 6
// 7110.268 us; speedup vs baseline: 1.1574x; 1.0072x over previous
//
#include <hip/hip_runtime.h>
#include <cstdint>
#include <cstddef>

#define NEGV -1.0e9f
#define TB 256
#define GT 4              // tiles per side (1024/TB)

// Branchless logaddexp, bit-identical to the verified branch form:
//   d>0 : a + log1pf(expf(-d))   -> m=a, -|d| = -d
//   d<=0: b + log1pf(expf(d))    -> m=b, -|d| = d
__device__ __forceinline__ float lse_f(float a, float b) {
    float d = a - b;
    float m = fmaxf(a, b);
    return m + log1pf(expf(-fabsf(d)));
}

__device__ __forceinline__ float cellfwd(float th, float vu, float vdg, float vl, float A) {
    float inner = lse_f(vu + A, vdg);
    float outer = lse_f(inner, vl + A);
    return th + outer;
}

// ---------------------------------------------------------------------------
// K1: T = emb @ W + b   (f64 accumulate), T: [22][512]
// ---------------------------------------------------------------------------
__global__ void k_embed(const float* __restrict__ emb, const float* __restrict__ W,
                        const float* __restrict__ b, double* __restrict__ T) {
    int idx = blockIdx.x * blockDim.x + threadIdx.x;
    if (idx >= 22 * 512) return;
    int a = idx >> 9, d = idx & 511;
    double acc = (double)b[d];
    const float* er = emb + a * 512;
    for (int k = 0; k < 512; ++k) acc += (double)er[k] * (double)W[k * 512 + d];
    T[idx] = acc;
}

// ---------------------------------------------------------------------------
// K2: G = T @ T^T (22x22), u1/u2 = T @ Wg halves, A[b] via index sums
// ---------------------------------------------------------------------------
__global__ void k_gau(const double* __restrict__ T, const int* __restrict__ x,
                      const int* __restrict__ y, const float* __restrict__ Wg,
                      const float* __restrict__ bg,
                      double* __restrict__ G, double* __restrict__ Aout) {
    __shared__ double u1s[22], u2s[22];
    int t = threadIdx.x;
    if (t < 484) {
        int a = t / 22, c = t % 22;
        const double* ra = T + a * 512;
        const double* rc = T + c * 512;
        double acc = 0.0;
        for (int d = 0; d < 512; ++d) acc += ra[d] * rc[d];
        G[t] = acc;
    }
    if (t < 22) {
        double acc = 0.0;
        const double* ra = T + t * 512;
        for (int d = 0; d < 512; ++d) acc += ra[d] * (double)Wg[d];
        u1s[t] = acc;
    } else if (t >= 64 && t < 86) {
        int a = t - 64;
        double acc = 0.0;
        const double* ra = T + a * 512;
        for (int d = 0; d < 512; ++d) acc += ra[d] * (double)Wg[512 + d];
        u2s[a] = acc;
    }
    __syncthreads();
    int w = t >> 6, lane = t & 63;
    const int* xb = x + w * 1024;
    const int* yb = y + w * 1024;
    double s = 0.0;
    for (int i = lane; i < 1024; i += 64) s += u1s[xb[i]] + u2s[yb[i]];
    for (int off = 32; off > 0; off >>= 1) s += __shfl_down(s, off);
    if (lane == 0) Aout[w] = s * (1.0 / 1024.0) + (double)bg[0];
}

// ---------------------------------------------------------------------------
// K3a: init V boundary (row 0 / col 0). Vbuf[b][i][j], stride 1025.
// ---------------------------------------------------------------------------
__global__ void k_vinit(float* __restrict__ Vbuf) {
    int b = blockIdx.x, t = threadIdx.x;
    float* Vb = Vbuf + (size_t)b * (1025 * 1025);
    Vb[t] = (t == 0) ? 0.0f : NEGV;                 // V[0][t]
    if (t == 0) Vb[1024] = NEGV;                    // V[0][1024]
    Vb[(size_t)(t + 1) * 1025] = NEGV;              // V[t+1][0]
}

// ---------------------------------------------------------------------------
// K3b: single-wave forward tile (256x256). Lane l owns rows 4l..4l+3; V
//      carried in registers, neighbor row via __shfl_up. NO barriers.
//      Per-cell float ops bit-identical to the verified kernel.
// ---------------------------------------------------------------------------
__global__ __launch_bounds__(64) void k_fwd64(const int* __restrict__ x,
                                              const int* __restrict__ y,
                                              const double* __restrict__ G,
                                              const double* __restrict__ Aarr,
                                              float* __restrict__ Vbuf,
                                              int d, int cnt, int rlo) {
    __shared__ float Gs[484];
    __shared__ float topv[TB + 1], leftv[TB + 1];
    __shared__ int ys[TB];

    const int t = threadIdx.x;            // lane
    const int b = blockIdx.x / cnt;
    const int r = rlo + (blockIdx.x % cnt);
    const int c = d - r;
    const int r0 = TB * r, c0 = TB * c;
    float* Vb = Vbuf + (size_t)b * (1025 * 1025);

    for (int q = t; q < 484; q += 64) Gs[q] = (float)G[q];
    for (int q = t; q < TB + 1; q += 64) {
        topv[q]  = Vb[(size_t)r0 * 1025 + c0 + q];
        leftv[q] = Vb[(size_t)(r0 + q) * 1025 + c0];
    }
    for (int q = t; q < TB; q += 64) ys[q] = y[(b << 10) + c0 + q];
    const int xb = (b << 10) + r0 + 4 * t;
    const int xs0 = x[xb], xs1 = x[xb + 1], xs2 = x[xb + 2], xs3 = x[xb + 3];
    __syncthreads();

    const float A = (float)Aarr[b];
    const float* G0 = Gs + xs0 * 22;
    const float* G1 = Gs + xs1 * 22;
    const float* G2 = Gs + xs2 * 22;
    const float* G3 = Gs + xs3 * 22;
    float* vst = Vb + (size_t)(r0 + 1 + 4 * t) * 1025 + (c0 + 1);

    float vp0 = 0.f, vp1 = 0.f, vp2 = 0.f, vp3 = 0.f, sdiag = 0.f;

    for (int s = 0; s < TB + 63; ++s) {
        float up = __shfl_up(vp3, 1);     // lane l-1 bottom row @ col lj
        const int lj = s - t;
        if (lj >= 0 && lj < TB) {
            const int yc = ys[lj];
            const float th0 = G0[yc], th1 = G1[yc], th2 = G2[yc], th3 = G3[yc];
            float vu0 = (t == 0) ? topv[lj + 1] : up;
            float dg0;
            if (lj == 0) {                // seed carries from left halo
                dg0 = leftv[4 * t];
                vp0 = leftv[4 * t + 1];
                vp1 = leftv[4 * t + 2];
                vp2 = leftv[4 * t + 3];
                vp3 = leftv[4 * t + 4];
            } else {
                dg0 = (t == 0) ? topv[lj] : sdiag;
            }
            float v0 = cellfwd(th0, vu0, dg0, vp0, A);
            float v1 = cellfwd(th1, v0,  vp0, vp1, A);
            float v2 = cellfwd(th2, v1,  vp1, vp2, A);
            float v3 = cellfwd(th3, v2,  vp2, vp3, A);
            vst[lj]            = v0;      // stores stay in flight
            vst[lj + 1025]     = v1;
            vst[lj + 2 * 1025] = v2;
            vst[lj + 3 * 1025] = v3;
            vp0 = v0; vp1 = v1; vp2 = v2; vp3 = v3;
        }
        sdiag = up;                       // lane l-1 bottom @ col lj-1 next step
    }
}

// ---------------------------------------------------------------------------
// K4: weight kernel — recompute each cell's softmax weights (bit-identical
//     inputs from stored V), scatter into the CONSUMER cell's float3 bundle:
//     bundle(I,J) = { wu(I+1,J), wd(I+1,J+1), wl(I,J+1) }  (bi=I-1, bj=J-1)
// ---------------------------------------------------------------------------
__global__ __launch_bounds__(256) void k_wb(const double* __restrict__ Aarr,
                                            const float* __restrict__ Vbuf,
                                            float* __restrict__ bw) {
    int idx = blockIdx.x * 256 + threadIdx.x;
    int b = idx >> 20;
    int cell = idx & 1048575;
    int i = (cell >> 10) + 1;        // 1..1024
    int j = (cell & 1023) + 1;       // 1..1024
    const float* Vb = Vbuf + (size_t)b * (1025 * 1025);
    float vu  = Vb[(size_t)(i - 1) * 1025 + j];
    float vdg = Vb[(size_t)(i - 1) * 1025 + (j - 1)];
    float vl  = Vb[(size_t)i * 1025 + (j - 1)];
    float A = (float)Aarr[b];
    float t1 = vu + A;
    float t2 = vl + A;
    float di = t1 - vdg;
    float inner = (di > 0.f) ? (t1  + log1pf(expf(-di)))
                             : (vdg + log1pf(expf(di)));
    float dw = inner - t2;
    float outer = (dw > 0.f) ? (inner + log1pf(expf(-dw)))
                             : (t2    + log1pf(expf(dw)));
    float go1 = expf(inner - outer);
    float wlW = expf(t2 - outer);
    float wuW = go1 * expf(t1 - inner);
    float wdW = go1 * expf(vdg - inner);
    float* bbp = bw + ((size_t)b << 20) * 3;
    if (i >= 2)           bbp[((size_t)(i - 2) * 1024 + (j - 1)) * 3 + 0] = wuW;
    if (i >= 2 && j >= 2) bbp[((size_t)(i - 2) * 1024 + (j - 2)) * 3 + 1] = wdW;
    if (j >= 2)           bbp[((size_t)(i - 1) * 1024 + (j - 2)) * 3 + 2] = wlW;
}

// ---------------------------------------------------------------------------
// K5: single-wave backward tile (mirror of k_fwd64). Lane l owns rows
//     4l..4l+3, cols processed descending; neighbor row via __shfl_down;
//     one float3 bundle load per cell (prefetched one column ahead);
//     coalesced float4 store into transposed out. NO barriers.
// ---------------------------------------------------------------------------
__global__ __launch_bounds__(64) void k_bwd64(const float* __restrict__ bw,
                                              float* __restrict__ out,
                                              int d, int cnt, int rlo) {
    __shared__ float botE[TB + 1], rightE[TB + 1];

    const int t = threadIdx.x;
    const int b = blockIdx.x / cnt;
    const int r = rlo + (blockIdx.x % cnt);
    const int c = d - r;
    const int r0 = TB * r, c0 = TB * c;
    const float* bb = bw + ((size_t)b << 20) * 3;
    float* ob = out + ((size_t)b << 20);

    const int gi = r0 + TB + 1;       // halo row below (global i)
    const int gj = c0 + TB + 1;       // halo col right (global j)
    for (int q = t; q < TB; q += 64) {
        botE[q]   = (gi <= 1024) ? ob[(size_t)(c0 + q) * 1024 + (gi - 1)] : 0.f;
        rightE[q] = (gj <= 1024) ? ob[(size_t)(gj - 1) * 1024 + (r0 + q)] : 0.f;
    }
    if (t == 0) {
        float corner = (gi <= 1024 && gj <= 1024)
                     ? ob[(size_t)(gj - 1) * 1024 + (gi - 1)] : 0.f;
        botE[TB] = corner; rightE[TB] = corner;
    }
    __syncthreads();

    const int row0 = r0 + 4 * t;              // bundle row (= global i - 1)
    const bool bottom = (t == 63);
    const bool lastlane = (r == GT - 1) && (c == GT - 1) && (t == 63);

    float ep0 = 0.f, ep1 = 0.f, ep2 = 0.f, ep3 = 0.f, sdb = 0.f;
    float c0x = 0, c0y = 0, c0z = 0, c1x = 0, c1y = 0, c1z = 0;
    float c2x = 0, c2y = 0, c2z = 0, c3x = 0, c3y = 0, c3z = 0;

    for (int s = 0; s < TB + 63; ++s) {
        float dn = __shfl_down(ep0, 1);   // lane l+1 top row @ col lj
        const int lj = (TB - 1) - (s - (63 - t));
        if (lj >= 0 && lj < TB) {
            if (lj == TB - 1) {           // seed from right halo + first bundles
                ep0 = rightE[4 * t];     ep1 = rightE[4 * t + 1];
                ep2 = rightE[4 * t + 2]; ep3 = rightE[4 * t + 3];
                const size_t base = ((size_t)row0 * 1024 + (c0 + lj)) * 3;
                float3 B0 = *(const float3*)(bb + base);
                float3 B1 = *(const float3*)(bb + base + 3072);
                float3 B2 = *(const float3*)(bb + base + 6144);
                float3 B3 = *(const float3*)(bb + base + 9216);
                c0x = B0.x; c0y = B0.y; c0z = B0.z;
                c1x = B1.x; c1y = B1.y; c1z = B1.z;
                c2x = B2.x; c2y = B2.y; c2z = B2.z;
                c3x = B3.x; c3y = B3.y; c3z = B3.z;
            }
            float eu3 = bottom ? botE[lj] : dn;
            float ed3 = (lj == TB - 1) ? rightE[4 * t + 4]
                       : (bottom ? botE[lj + 1] : sdb);
            float e3 = eu3 * c3x + ed3 * c3y + ep3 * c3z;
            if (lastlane && lj == TB - 1) e3 = 1.0f;   // E[1024][1024] = 1
            float e2 = e3 * c2x + ep3 * c2y + ep2 * c2z;
            float e1 = e2 * c1x + ep2 * c1y + ep1 * c1z;
            float e0 = e1 * c0x + ep1 * c0y + ep0 * c0z;
            *(float4*)(ob + (size_t)(c0 + lj) * 1024 + row0)
                = make_float4(e0, e1, e2, e3);
            ep0 = e0; ep1 = e1; ep2 = e2; ep3 = e3;
            if (lj > 0) {                 // prefetch next column's bundles
                const size_t base = ((size_t)row0 * 1024 + (c0 + lj - 1)) * 3;
                float3 B0 = *(const float3*)(bb + base);
                float3 B1 = *(const float3*)(bb + base + 3072);
                float3 B2 = *(const float3*)(bb + base + 6144);
                float3 B3 = *(const float3*)(bb + base + 9216);
                c0x = B0.x; c0y = B0.y; c0z = B0.z;
                c1x = B1.x; c1y = B1.y; c1z = B1.z;
                c2x = B2.x; c2y = B2.y; c2z = B2.z;
                c3x = B3.x; c3y = B3.y; c3z = B3.z;
            }
        }
        sdb = dn;                         // lane l+1 top @ col lj+1 next step
    }
}

// ---------------------------------------------------------------------------
// Fallback: round-2 monolithic forward+backward (used only if ws too small).
// ---------------------------------------------------------------------------
template <bool FAITHFUL>
__global__ __launch_bounds__(1024) void k_dp(const int* __restrict__ x,
                                             const int* __restrict__ y,
                                             const double* __restrict__ G,
                                             const double* __restrict__ Aarr,
                                             float2* __restrict__ wbuf,
                                             float* __restrict__ wdbuf,
                                             float* __restrict__ out) {
    __shared__ float Gs[484];
    __shared__ int xs[1024], ys[1024];
    __shared__ float D[3][1025];
    __shared__ float E[3][1026];

    const int b = blockIdx.x;
    const int t = threadIdx.x;
    const int i = t + 1;

    if (t < 484) Gs[t] = (float)G[t];
    xs[t] = x[(b << 10) + t];
    ys[t] = y[(b << 10) + t];
    D[0][t + 1] = NEGV;
    D[1][t + 1] = NEGV;
    E[0][t] = 0.f; E[1][t] = 0.f; E[2][t] = 0.f;
    if (t == 0) {
        D[0][0] = 0.0f;
        D[1][0] = NEGV;
        E[0][1024] = 0.f; E[0][1025] = 0.f;
        E[1][1024] = 0.f; E[1][1025] = 0.f;
        E[2][1024] = 0.f; E[2][1025] = 0.f;
    }
    __syncthreads();

    const float A = (float)Aarr[b];
    const float* Grow = Gs + xs[t] * 22;
    float2* wb = wbuf + ((size_t)b << 20);
    float*  wdb = wdbuf + ((size_t)b << 20);

    for (int k = 2; k <= 2048; ++k) {
        const int cur = k % 3, p1 = (k + 2) % 3, p2 = (k + 1) % 3;
        const int j = k - i;
        if (j >= 1 && j <= 1024) {
            float vu  = D[p1][i - 1];
            float vdg = D[p2][i - 1];
            float vl  = D[p1][i];
            float t1 = vu + A;
            float t2 = vl + A;
            float di = t1 - vdg;
            float inner = (di > 0.f) ? (t1  + log1pf(expf(-di)))
                                     : (vdg + log1pf(expf(di)));
            float dw = inner - t2;
            float outer = (dw > 0.f) ? (inner + log1pf(expf(-dw)))
                                     : (t2    + log1pf(expf(dw)));
            D[cur][i] = Grow[ys[j - 1]] + outer;
            float go1 = expf(inner - outer);
            float wlW = expf(t2 - outer);
            float wuW = go1 * expf(t1 - inner);
            size_t ci = ((size_t)t << 10) + (j - 1);
            wb[ci] = make_float2(wuW, wlW);
            if (FAITHFUL) wdb[ci] = go1 * expf(vdg - inner);
        }
        if (t == 0) D[cur][0] = NEGV;
        if (i == k && k <= 1024) D[cur][k] = NEGV;
        __syncthreads();
    }

    __syncthreads();

    float* ob = out + ((size_t)b << 20);

    for (int k = 2048; k >= 2; --k) {
        const int cur = k % 3, n1 = (k + 1) % 3, n2 = (k + 2) % 3;
        const int j = k - i;
        if (j >= 1 && j <= 1024) {
            float e;
            if (k == 2048) {
                e = 1.0f;
            } else {
                float Eu = E[n1][i + 1];
                float Ed = E[n2][i + 1];
                float El = E[n1][i];
                int iw = (i < 1024) ? i : 1023;
                int jw = (j < 1024) ? j : 1023;
                float2 w_up = wb[((size_t)iw << 10) + (j - 1)];
                float2 w_lf = wb[((size_t)(i - 1) << 10) + jw];
                float w_dd;
                if (FAITHFUL) {
                    w_dd = wdb[((size_t)iw << 10) + jw];
                } else {
                    float2 w_dg = wb[((size_t)iw << 10) + jw];
                    w_dd = 1.0f - w_dg.x - w_dg.y;
                }
                e = Eu * w_up.x + Ed * w_dd + El * w_lf.y;
            }
            E[cur][i] = e;
            ob[((size_t)(j - 1) << 10) + (i - 1)] = e;
        } else {
            E[cur][i] = 0.f;
        }
        __syncthreads();
    }
}

// ---------------------------------------------------------------------------
extern "C" void kernel_launch(void* const* d_in, const int* in_sizes, int n_in,
                              void* d_out, int out_size, void* d_ws, size_t ws_size,
                              hipStream_t stream) {
    const int*   x   = (const int*)d_in[0];
    const int*   y   = (const int*)d_in[1];
    const float* emb = (const float*)d_in[2];
    const float* W   = (const float*)d_in[3];
    const float* b   = (const float*)d_in[4];
    const float* Wg  = (const float*)d_in[5];
    const float* bg  = (const float*)d_in[6];
    float* out = (float*)d_out;

    char* ws = (char*)d_ws;
    double* T    = (double*)(ws + 0);                       // 90112 B
    double* G    = (double*)(ws + 90112);                   // 3872 B
    double* Aarr = (double*)(ws + 94336);                   // 64 B
    float*  bund = (float*)(ws + 131072);                   // 96 MiB bundles
    float2* wbuf = (float2*)(ws + 131072);                  // (fallback layout)
    float*  wdbuf = (float*)(ws + 131072 + ((size_t)64 << 20));
    float*  Vbuf = (float*)(ws + 131072 + ((size_t)96 << 20));   // 33.6 MB

    k_embed<<<44, 256, 0, stream>>>(emb, W, b, T);
    k_gau<<<1, 512, 0, stream>>>(T, x, y, Wg, bg, G, Aarr);

    const size_t need_old = 131072 + ((size_t)96 << 20);
    const size_t need_new = need_old + (size_t)8 * 1025 * 1025 * 4;

    if (ws_size >= need_new) {
        k_vinit<<<8, 1024, 0, stream>>>(Vbuf);
        for (int d = 0; d < 2 * GT - 1; ++d) {
            int rlo = (d - (GT - 1) > 0) ? d - (GT - 1) : 0;
            int rhi = (d < GT - 1) ? d : GT - 1;
            int cnt = rhi - rlo + 1;
            k_fwd64<<<cnt * 8, 64, 0, stream>>>(x, y, G, Aarr, Vbuf, d, cnt, rlo);
        }
        k_wb<<<8 * 1024 * 1024 / 256, 256, 0, stream>>>(Aarr, Vbuf, bund);
        for (int d = 2 * GT - 2; d >= 0; --d) {
            int rlo = (d - (GT - 1) > 0) ? d - (GT - 1) : 0;
            int rhi = (d < GT - 1) ? d : GT - 1;
            int cnt = rhi - rlo + 1;
            k_bwd64<<<cnt * 8, 64, 0, stream>>>(bund, out, d, cnt, rlo);
        }
    } else if (ws_size >= need_old) {
        k_dp<true><<<8, 1024, 0, stream>>>(x, y, G, Aarr, wbuf, wdbuf, out);
    } else {
        k_dp<false><<<8, 1024, 0, stream>>>(x, y, G, Aarr, wbuf, wdbuf, out);
    }
}

// Round 8
// 4567.500 us; speedup vs baseline: 1.8017x; 1.5567x over previous
//
#include <hip/hip_runtime.h>
#include <cstdint>
#include <cstddef>

#define NEGV -1.0e9f
#define FT 64             // forward tile: 64 rows (1 wave, 1 row/lane) x 64 cols
#define NFT 16            // 1024 / FT

// Branchless logaddexp, bit-identical to the verified branch form.
__device__ __forceinline__ float lse_f(float a, float b) {
    float d = a - b;
    float m = fmaxf(a, b);
    return m + log1pf(expf(-fabsf(d)));
}
__device__ __forceinline__ float cellfwd(float th, float vu, float vdg, float vl, float A) {
    float inner = lse_f(vu + A, vdg);
    float outer = lse_f(inner, vl + A);
    return th + outer;
}

// ---------------------------------------------------------------------------
// K1: T = emb @ W + b   (f64 accumulate), T: [22][512]
// ---------------------------------------------------------------------------
__global__ void k_embed(const float* __restrict__ emb, const float* __restrict__ W,
                        const float* __restrict__ b, double* __restrict__ T) {
    int idx = blockIdx.x * blockDim.x + threadIdx.x;
    if (idx >= 22 * 512) return;
    int a = idx >> 9, d = idx & 511;
    double acc = (double)b[d];
    const float* er = emb + a * 512;
    for (int k = 0; k < 512; ++k) acc += (double)er[k] * (double)W[k * 512 + d];
    T[idx] = acc;
}

// ---------------------------------------------------------------------------
// K2: G = T @ T^T (22x22), u1/u2 = T @ Wg halves, A[b] via index sums
// ---------------------------------------------------------------------------
__global__ void k_gau(const double* __restrict__ T, const int* __restrict__ x,
                      const int* __restrict__ y, const float* __restrict__ Wg,
                      const float* __restrict__ bg,
                      double* __restrict__ G, double* __restrict__ Aout) {
    __shared__ double u1s[22], u2s[22];
    int t = threadIdx.x;
    if (t < 484) {
        int a = t / 22, c = t % 22;
        const double* ra = T + a * 512;
        const double* rc = T + c * 512;
        double acc = 0.0;
        for (int d = 0; d < 512; ++d) acc += ra[d] * rc[d];
        G[t] = acc;
    }
    if (t < 22) {
        double acc = 0.0;
        const double* ra = T + t * 512;
        for (int d = 0; d < 512; ++d) acc += ra[d] * (double)Wg[d];
        u1s[t] = acc;
    } else if (t >= 64 && t < 86) {
        int a = t - 64;
        double acc = 0.0;
        const double* ra = T + a * 512;
        for (int d = 0; d < 512; ++d) acc += ra[d] * (double)Wg[512 + d];
        u2s[a] = acc;
    }
    __syncthreads();
    int w = t >> 6, lane = t & 63;
    const int* xb = x + w * 1024;
    const int* yb = y + w * 1024;
    double s = 0.0;
    for (int i = lane; i < 1024; i += 64) s += u1s[xb[i]] + u2s[yb[i]];
    for (int off = 32; off > 0; off >>= 1) s += __shfl_down(s, off);
    if (lane == 0) Aout[w] = s * (1.0 / 1024.0) + (double)bg[0];
}

// ---------------------------------------------------------------------------
// K3a: init V boundary (row 0 / col 0). Vbuf[b][i][j], stride 1025.
// ---------------------------------------------------------------------------
__global__ void k_vinit(float* __restrict__ Vbuf) {
    int b = blockIdx.x, t = threadIdx.x;
    float* Vb = Vbuf + (size_t)b * (1025 * 1025);
    Vb[t] = (t == 0) ? 0.0f : NEGV;                 // V[0][t]
    if (t == 0) Vb[1024] = NEGV;                    // V[0][1024]
    Vb[(size_t)(t + 1) * 1025] = NEGV;              // V[t+1][0]
}

// ---------------------------------------------------------------------------
// K3b: single-wave forward tile (64x64, 1 row/lane). V carried in registers,
//      up-neighbor via __shfl_up, diag via carry (vdg <- prev vu). NO barriers.
//      Per-cell float ops bit-identical to the verified kernels.
// ---------------------------------------------------------------------------
__global__ __launch_bounds__(64) void k_fwd1(const int* __restrict__ x,
                                             const int* __restrict__ y,
                                             const double* __restrict__ G,
                                             const double* __restrict__ Aarr,
                                             float* __restrict__ Vbuf,
                                             int d, int cnt, int rlo) {
    __shared__ float Gs[484];
    __shared__ float topv[FT + 1], leftv[FT + 1];
    __shared__ int ys_s[FT];

    const int t = threadIdx.x;
    const int b = blockIdx.x / cnt;
    const int r = rlo + (blockIdx.x % cnt);
    const int c = d - r;
    const int r0 = FT * r, c0 = FT * c;
    float* Vb = Vbuf + (size_t)b * (1025 * 1025);

    for (int q = t; q < 484; q += 64) Gs[q] = (float)G[q];
    ys_s[t] = y[(b << 10) + c0 + t];
    const int xs = x[(b << 10) + r0 + t];
    topv[t]  = Vb[(size_t)r0 * 1025 + c0 + t];
    leftv[t] = Vb[(size_t)(r0 + t) * 1025 + c0];
    if (t == 0) {
        topv[FT]  = Vb[(size_t)r0 * 1025 + c0 + FT];
        leftv[FT] = Vb[(size_t)(r0 + FT) * 1025 + c0];
    }
    __syncthreads();

    const float A = (float)Aarr[b];
    const float* Grow = Gs + xs * 22;
    float* vst = Vb + (size_t)(r0 + 1 + t) * 1025 + (c0 + 1);

    float vp = 0.f, vdgc = 0.f;
    for (int s = 0; s < FT + 63; ++s) {
        float ush = __shfl_up(vp, 1);     // lane t-1's v at col lj
        const int lj = s - t;
        if (lj >= 0 && lj < FT) {
            float vu  = (t == 0) ? topv[lj + 1] : ush;
            float vdg = (lj == 0) ? leftv[t] : vdgc;
            float vl  = (lj == 0) ? leftv[t + 1] : vp;
            float v = cellfwd(Grow[ys_s[lj]], vu, vdg, vl, A);
            vst[lj] = v;                  // store stays in flight
            vp = v; vdgc = vu;
        }
    }
}

// ---------------------------------------------------------------------------
// K4: weight kernel — recompute each cell's softmax weights (bit-identical
//     inputs from stored V), scatter into the CONSUMER cell's float3 bundle:
//     bundle(I,J) = { wu(I+1,J), wd(I+1,J+1), wl(I,J+1) }  at (I-1)*1024+(J-1)
// ---------------------------------------------------------------------------
__global__ __launch_bounds__(256) void k_wb(const double* __restrict__ Aarr,
                                            const float* __restrict__ Vbuf,
                                            float* __restrict__ bw) {
    int idx = blockIdx.x * 256 + threadIdx.x;
    int b = idx >> 20;
    int cell = idx & 1048575;
    int i = (cell >> 10) + 1;        // 1..1024
    int j = (cell & 1023) + 1;       // 1..1024
    const float* Vb = Vbuf + (size_t)b * (1025 * 1025);
    float vu  = Vb[(size_t)(i - 1) * 1025 + j];
    float vdg = Vb[(size_t)(i - 1) * 1025 + (j - 1)];
    float vl  = Vb[(size_t)i * 1025 + (j - 1)];
    float A = (float)Aarr[b];
    float t1 = vu + A;
    float t2 = vl + A;
    float di = t1 - vdg;
    float inner = (di > 0.f) ? (t1  + log1pf(expf(-di)))
                             : (vdg + log1pf(expf(di)));
    float dw = inner - t2;
    float outer = (dw > 0.f) ? (inner + log1pf(expf(-dw)))
                             : (t2    + log1pf(expf(dw)));
    float go1 = expf(inner - outer);
    float wlW = expf(t2 - outer);
    float wuW = go1 * expf(t1 - inner);
    float wdW = go1 * expf(vdg - inner);
    float* bbp = bw + ((size_t)b << 20) * 3;
    if (i >= 2)           bbp[((size_t)(i - 2) * 1024 + (j - 1)) * 3 + 0] = wuW;
    if (i >= 2 && j >= 2) bbp[((size_t)(i - 2) * 1024 + (j - 2)) * 3 + 1] = wdW;
    if (j >= 2)           bbp[((size_t)(i - 1) * 1024 + (j - 2)) * 3 + 2] = wlW;
}

// ---------------------------------------------------------------------------
// K5: single-launch backward. One wave per batch; lane t owns global rows
//     16t+1..16t+16; sweeps columns 1024..1 (cj = j-1 descending). Same
//     dependency pattern as the verified k_bwd64 (shfl_down + sdb carry),
//     RP=16, no halos (global boundary is all zeros). Cell expression
//     verbatim: e = eu*wu + ed*wd + el*wl. Sequential cell order preserved
//     => bit-identical to the verified backward.
// ---------------------------------------------------------------------------
__global__ __launch_bounds__(64) void k_bwd16(const float* __restrict__ bw,
                                              float* __restrict__ out) {
    const int t = threadIdx.x;
    const int b = blockIdx.x;
    const float* bb = bw + ((size_t)b << 20) * 3;
    float* ob = out + ((size_t)b << 20);
    const int r0 = t << 4;              // (i-1) base = 16t

    float e[16];
    float3 cw[16], pf[16];
    #pragma unroll
    for (int q = 0; q < 16; ++q) e[q] = 0.f;

    // preload col 1023 (every lane's first active column is j=1024)
    #pragma unroll
    for (int q = 0; q < 16; ++q)
        cw[q] = *(const float3*)(bb + ((size_t)(r0 + q) * 1024 + 1023) * 3);

    float sdb = 0.f;
    for (int s = 0; s < 1087; ++s) {
        float dn = __shfl_down(e[0], 1);    // lane t+1's top value at col cj
        const int cj = 1086 - s - t;        // this lane's column (j-1)
        if (cj >= 0 && cj < 1024) {
            // prefetch next column's bundles (clamped; unused at cj==0)
            const int cn = (cj > 0) ? cj - 1 : 0;
            #pragma unroll
            for (int q = 0; q < 16; ++q)
                pf[q] = *(const float3*)(bb + ((size_t)(r0 + q) * 1024 + cn) * 3);

            // q = 15 (bottom row of the lane's strip)
            float old_b = e[15];            // old E[i][j+1] for this row
            float eu = (t == 63) ? 0.f : dn;        // E[i+1][j]
            float ed = (t == 63) ? 0.f : sdb;       // E[i+1][j+1]
            float v = eu * cw[15].x + ed * cw[15].y + old_b * cw[15].z;
            if (t == 63 && cj == 1023) v = 1.0f;    // seed E[1024][1024] = 1
            e[15] = v;
            float new_b = v;
            // q = 14..0: eu = new e[q+1], ed = old e[q+1], el = old e[q]
            #pragma unroll
            for (int q = 14; q >= 0; --q) {
                float oq = e[q];
                v = new_b * cw[q].x + old_b * cw[q].y + oq * cw[q].z;
                e[q] = v;
                new_b = v; old_b = oq;
            }
            // store 16 consecutive rows at column cj (out[j-1][i-1])
            #pragma unroll
            for (int k = 0; k < 4; ++k)
                *(float4*)&ob[(size_t)cj * 1024 + r0 + 4 * k] =
                    make_float4(e[4*k], e[4*k+1], e[4*k+2], e[4*k+3]);
            // rotate prefetch
            #pragma unroll
            for (int q = 0; q < 16; ++q) cw[q] = pf[q];
        }
        sdb = dn;       // lane t+1's value at col cj+1 for next step
    }
}

// ---------------------------------------------------------------------------
// Fallback: round-2 monolithic forward+backward (used only if ws too small).
// ---------------------------------------------------------------------------
template <bool FAITHFUL>
__global__ __launch_bounds__(1024) void k_dp(const int* __restrict__ x,
                                             const int* __restrict__ y,
                                             const double* __restrict__ G,
                                             const double* __restrict__ Aarr,
                                             float2* __restrict__ wbuf,
                                             float* __restrict__ wdbuf,
                                             float* __restrict__ out) {
    __shared__ float Gs[484];
    __shared__ int xs[1024], ys[1024];
    __shared__ float D[3][1025];
    __shared__ float E[3][1026];

    const int b = blockIdx.x;
    const int t = threadIdx.x;
    const int i = t + 1;

    if (t < 484) Gs[t] = (float)G[t];
    xs[t] = x[(b << 10) + t];
    ys[t] = y[(b << 10) + t];
    D[0][t + 1] = NEGV;
    D[1][t + 1] = NEGV;
    E[0][t] = 0.f; E[1][t] = 0.f; E[2][t] = 0.f;
    if (t == 0) {
        D[0][0] = 0.0f;
        D[1][0] = NEGV;
        E[0][1024] = 0.f; E[0][1025] = 0.f;
        E[1][1024] = 0.f; E[1][1025] = 0.f;
        E[2][1024] = 0.f; E[2][1025] = 0.f;
    }
    __syncthreads();

    const float A = (float)Aarr[b];
    const float* Grow = Gs + xs[t] * 22;
    float2* wb = wbuf + ((size_t)b << 20);
    float*  wdb = wdbuf + ((size_t)b << 20);

    for (int k = 2; k <= 2048; ++k) {
        const int cur = k % 3, p1 = (k + 2) % 3, p2 = (k + 1) % 3;
        const int j = k - i;
        if (j >= 1 && j <= 1024) {
            float vu  = D[p1][i - 1];
            float vdg = D[p2][i - 1];
            float vl  = D[p1][i];
            float t1 = vu + A;
            float t2 = vl + A;
            float di = t1 - vdg;
            float inner = (di > 0.f) ? (t1  + log1pf(expf(-di)))
                                     : (vdg + log1pf(expf(di)));
            float dw = inner - t2;
            float outer = (dw > 0.f) ? (inner + log1pf(expf(-dw)))
                                     : (t2    + log1pf(expf(dw)));
            D[cur][i] = Grow[ys[j - 1]] + outer;
            float go1 = expf(inner - outer);
            float wlW = expf(t2 - outer);
            float wuW = go1 * expf(t1 - inner);
            size_t ci = ((size_t)t << 10) + (j - 1);
            wb[ci] = make_float2(wuW, wlW);
            if (FAITHFUL) wdb[ci] = go1 * expf(vdg - inner);
        }
        if (t == 0) D[cur][0] = NEGV;
        if (i == k && k <= 1024) D[cur][k] = NEGV;
        __syncthreads();
    }

    __syncthreads();

    float* ob = out + ((size_t)b << 20);

    for (int k = 2048; k >= 2; --k) {
        const int cur = k % 3, n1 = (k + 1) % 3, n2 = (k + 2) % 3;
        const int j = k - i;
        if (j >= 1 && j <= 1024) {
            float e;
            if (k == 2048) {
                e = 1.0f;
            } else {
                float Eu = E[n1][i + 1];
                float Ed = E[n2][i + 1];
                float El = E[n1][i];
                int iw = (i < 1024) ? i : 1023;
                int jw = (j < 1024) ? j : 1023;
                float2 w_up = wb[((size_t)iw << 10) + (j - 1)];
                float2 w_lf = wb[((size_t)(i - 1) << 10) + jw];
                float w_dd;
                if (FAITHFUL) {
                    w_dd = wdb[((size_t)iw << 10) + jw];
                } else {
                    float2 w_dg = wb[((size_t)iw << 10) + jw];
                    w_dd = 1.0f - w_dg.x - w_dg.y;
                }
                e = Eu * w_up.x + Ed * w_dd + El * w_lf.y;
            }
            E[cur][i] = e;
            ob[((size_t)(j - 1) << 10) + (i - 1)] = e;
        } else {
            E[cur][i] = 0.f;
        }
        __syncthreads();
    }
}

// ---------------------------------------------------------------------------
extern "C" void kernel_launch(void* const* d_in, const int* in_sizes, int n_in,
                              void* d_out, int out_size, void* d_ws, size_t ws_size,
                              hipStream_t stream) {
    const int*   x   = (const int*)d_in[0];
    const int*   y   = (const int*)d_in[1];
    const float* emb = (const float*)d_in[2];
    const float* W   = (const float*)d_in[3];
    const float* b   = (const float*)d_in[4];
    const float* Wg  = (const float*)d_in[5];
    const float* bg  = (const float*)d_in[6];
    float* out = (float*)d_out;

    char* ws = (char*)d_ws;
    double* T    = (double*)(ws + 0);                       // 90112 B
    double* G    = (double*)(ws + 90112);                   // 3872 B
    double* Aarr = (double*)(ws + 94336);                   // 64 B
    float*  bund = (float*)(ws + 131072);                   // 96 MiB bundles
    float2* wbuf = (float2*)(ws + 131072);                  // (fallback layout)
    float*  wdbuf = (float*)(ws + 131072 + ((size_t)64 << 20));
    float*  Vbuf = (float*)(ws + 131072 + ((size_t)96 << 20));   // 33.6 MB

    k_embed<<<44, 256, 0, stream>>>(emb, W, b, T);
    k_gau<<<1, 512, 0, stream>>>(T, x, y, Wg, bg, G, Aarr);

    const size_t need_old = 131072 + ((size_t)96 << 20);
    const size_t need_new = need_old + (size_t)8 * 1025 * 1025 * 4;

    if (ws_size >= need_new) {
        k_vinit<<<8, 1024, 0, stream>>>(Vbuf);
        for (int d = 0; d < 2 * NFT - 1; ++d) {
            int rlo = (d - (NFT - 1) > 0) ? d - (NFT - 1) : 0;
            int rhi = (d < NFT - 1) ? d : NFT - 1;
            int cnt = rhi - rlo + 1;
            k_fwd1<<<cnt * 8, 64, 0, stream>>>(x, y, G, Aarr, Vbuf, d, cnt, rlo);
        }
        k_wb<<<8 * 1024 * 1024 / 256, 256, 0, stream>>>(Aarr, Vbuf, bund);
        k_bwd16<<<8, 64, 0, stream>>>(bund, out);
    } else if (ws_size >= need_old) {
        k_dp<true><<<8, 1024, 0, stream>>>(x, y, G, Aarr, wbuf, wdbuf, out);
    } else {
        k_dp<false><<<8, 1024, 0, stream>>>(x, y, G, Aarr, wbuf, wdbuf, out);
    }
}